// Round 3
// baseline (638.761 us; speedup 1.0000x reference)
//
#include <hip/hip_runtime.h>

// MixerBlock: B=8, T=2048, E=1024, H=16, HD=64, DFF=4096, DC=4
// GEMM: 256x256 tile, BK=64, 8 waves (2Mx4N), double-buffered 128 KiB LDS,
//       8-phase schedule with COUNTED vmcnt (T3+T4), T1 XCD swizzle,
//       T2 both-sides XOR swizzle, T5 setprio. Raw s_barrier (no vmcnt(0)
//       drain in main loop).
// Per-wave vmcnt accounting (4 gloads per k-half per wave):
//   tile t phases: PH0 issue kh0(t+1); PH1 issue kh1(t+1), vmcnt(8) -> kh1(t)
//   landed (needed PH2); PH3 vmcnt(4) -> kh0(t+1) landed (needed next PH0).

#define TT 2048
#define EE 1024
#define HHD 64
#define MROWS 16384
#define SC_L 64

typedef __bf16 bf16x8 __attribute__((ext_vector_type(8)));
typedef float f32x4 __attribute__((ext_vector_type(4)));
typedef unsigned short u16;
typedef unsigned int u32;

__device__ __forceinline__ u16 f2bf(float f) {
  u32 u = __builtin_bit_cast(u32, f);
  u += 0x7FFFu + ((u >> 16) & 1u);      // round-to-nearest-even
  return (u16)(u >> 16);
}
__device__ __forceinline__ float bf2f(u16 s) {
  u32 u = ((u32)s) << 16;
  return __builtin_bit_cast(float, u);
}
__device__ __forceinline__ float gelu_f(float x) {
  float u = 0.7978845608028654f * x * (1.0f + 0.044715f * x * x);
  float e = __expf(2.0f * u);
  float t = 1.0f - 2.0f / (e + 1.0f);   // tanh(u)
  return 0.5f * x * (1.0f + t);
}
__device__ __forceinline__ void gload_lds16(const void* g, void* l) {
  __builtin_amdgcn_global_load_lds(
      (const __attribute__((address_space(1))) u32*)g,
      (__attribute__((address_space(3))) u32*)l, 16, 0, 0);
}
__device__ __forceinline__ void barrier_seq() {
  asm volatile("" ::: "memory");
  __builtin_amdgcn_s_barrier();
  asm volatile("" ::: "memory");
  __builtin_amdgcn_sched_barrier(0);
}

// ---------------- weight transpose + cast: src (R x C) f32 -> dst (C x R) bf16
__global__ __launch_bounds__(256) void transpose_to_bf16(
    const float* __restrict__ src, u16* __restrict__ dst, int R, int C,
    long sbs, long dbs) {
  __shared__ float tile[32][33];
  src += (long)blockIdx.z * sbs;
  dst += (long)blockIdx.z * dbs;
  int c0 = blockIdx.x * 32, r0 = blockIdx.y * 32;
  int tx = threadIdx.x, ty = threadIdx.y;
#pragma unroll
  for (int i = 0; i < 4; i++)
    tile[ty + i * 8][tx] = src[(long)(r0 + ty + i * 8) * C + c0 + tx];
  __syncthreads();
#pragma unroll
  for (int i = 0; i < 4; i++)
    dst[(long)(c0 + ty + i * 8) * R + r0 + tx] = f2bf(tile[tx][ty + i * 8]);
}

// ---------------- LayerNorm over E=1024, one row per block
__global__ __launch_bounds__(256) void ln_to_bf16(
    const float* __restrict__ x, const float* __restrict__ gam,
    const float* __restrict__ bet, u16* __restrict__ y) {
  int row = blockIdx.x;
  int tid = threadIdx.x;
  float4 v = ((const float4*)x)[row * 256 + tid];
  float s = v.x + v.y + v.z + v.w;
  float s2 = v.x * v.x + v.y * v.y + v.z * v.z + v.w * v.w;
#pragma unroll
  for (int off = 1; off < 64; off <<= 1) {
    s += __shfl_xor(s, off);
    s2 += __shfl_xor(s2, off);
  }
  __shared__ float red[8];
  int w = tid >> 6;
  if ((tid & 63) == 0) { red[w] = s; red[4 + w] = s2; }
  __syncthreads();
  s = red[0] + red[1] + red[2] + red[3];
  s2 = red[4] + red[5] + red[6] + red[7];
  float mu = s * (1.0f / 1024.0f);
  float var = s2 * (1.0f / 1024.0f) - mu * mu;
  float rstd = rsqrtf(var + 1e-5f);
  int e0 = tid * 4;
  ushort4 o;
  o.x = f2bf((v.x - mu) * rstd * gam[e0 + 0] + bet[e0 + 0]);
  o.y = f2bf((v.y - mu) * rstd * gam[e0 + 1] + bet[e0 + 1]);
  o.z = f2bf((v.z - mu) * rstd * gam[e0 + 2] + bet[e0 + 2]);
  o.w = f2bf((v.w - mu) * rstd * gam[e0 + 3] + bet[e0 + 3]);
  ((ushort4*)y)[row * 256 + tid] = o;
}

// ---------------- bf16 GEMM, 256x256 tile, BK=64, 8-phase counted-vmcnt.
// A: (M x K) bf16 row-major. Bt: (N x K) bf16 row-major.
// LDS buffer c at c*32768 (u16): A_ks0 [0,8192) A_ks1 [8192,16384)
//                                B_ks0 [16384,24576) B_ks1 [24576,32768)
// Sub-tile = [256 rows][4 slots of 8 bf16]; slot swizzled: LDS slot j holds
// global slot j^(row&3) (written via pre-swizzled global source, rule #21).
// EPI 0: bf16 = acc+bias ; 1: f32 = acc+bias+res ; 2: bf16 = gelu(acc+bias)
template <int EPI>
__global__ __launch_bounds__(512, 2) void gemm256(
    const u16* __restrict__ A, const u16* __restrict__ Bt,
    const float* __restrict__ bias, const float* __restrict__ res, void* outp,
    int M, int N, int K) {
  __shared__ u16 lds[65536];  // 128 KiB
  const int tid = threadIdx.x;
  const int w = tid >> 6, lane = tid & 63;
  const int wm = w >> 2, wn = w & 3;
  const int l15 = lane & 15, lk = lane >> 4;

  // T1: bijective XCD swizzle (all launches have nwg % 8 == 0)
  const int gx = (int)gridDim.x;
  const int nwg = gx * (int)gridDim.y;
  const int bid = (int)blockIdx.y * gx + (int)blockIdx.x;
  const int cpx = nwg >> 3;
  const int swz = (bid & 7) * cpx + (bid >> 3);
  const int bx = swz % gx, by = swz / gx;
  const int m0 = by * 256, n0 = bx * 256;

  // Staging: per k-half, per matrix: 2 block-issues of 128 rows each.
  // Thread covers row srow(+128*i), 16B slot (lane&3), source pre-swizzled.
  const int srow = w * 16 + (lane >> 2);
  const int ssl = ((lane & 3) ^ ((lane >> 2) & 3)) * 8;
  const u16* aS0 = A + (size_t)(m0 + srow) * K + ssl;
  const u16* aS1 = A + (size_t)(m0 + 128 + srow) * K + ssl;
  const u16* bS0 = Bt + (size_t)(n0 + srow) * K + ssl;
  const u16* bS1 = Bt + (size_t)(n0 + 128 + srow) * K + ssl;

  // Compute-side LDS bases (u16 units), read-side swizzle lk^(l15&3)
  const int swr = ((lk ^ (l15 & 3)) << 3);
  const int aBase = (wm * 128 + l15) * 32 + swr;
  const int bBase = 16384 + (wn * 64 + l15) * 32 + swr;

  f32x4 acc[8][4];
  const f32x4 z = {0.f, 0.f, 0.f, 0.f};
#pragma unroll
  for (int mi = 0; mi < 8; mi++)
#pragma unroll
    for (int ni = 0; ni < 4; ni++) acc[mi][ni] = z;

  bf16x8 a[4], b[4];

#define STAGE_KH(C, KT, KH) { \
    u16* lb = lds + (C) * 32768 + (KH) * 8192 + w * 512; \
    const int ko = (KT) + (KH) * 32; \
    gload_lds16(aS0 + ko, lb); \
    gload_lds16(aS1 + ko, lb + 4096); \
    gload_lds16(bS0 + ko, lb + 16384); \
    gload_lds16(bS1 + ko, lb + 20480); }

#define RD_A(C, KS, CH) { \
    const u16* lp = lds + (C) * 32768 + (KS) * 8192 + aBase + (CH) * 2048; \
    a[0] = *(const bf16x8*)(lp); \
    a[1] = *(const bf16x8*)(lp + 512); \
    a[2] = *(const bf16x8*)(lp + 1024); \
    a[3] = *(const bf16x8*)(lp + 1536); }

#define RD_B(C, KS) { \
    const u16* lp = lds + (C) * 32768 + (KS) * 8192 + bBase; \
    b[0] = *(const bf16x8*)(lp); \
    b[1] = *(const bf16x8*)(lp + 512); \
    b[2] = *(const bf16x8*)(lp + 1024); \
    b[3] = *(const bf16x8*)(lp + 1536); }

#define MFMA16(CH) { \
    __builtin_amdgcn_s_setprio(1); \
    _Pragma("unroll") \
    for (int mm = 0; mm < 4; mm++) \
      _Pragma("unroll") \
      for (int nn = 0; nn < 4; nn++) \
        acc[(CH) * 4 + mm][nn] = __builtin_amdgcn_mfma_f32_16x16x32_bf16( \
            a[mm], b[nn], acc[(CH) * 4 + mm][nn], 0, 0, 0); \
    __builtin_amdgcn_s_setprio(0); }

  const int nt = K >> 6;
  STAGE_KH(0, 0, 0);
  STAGE_KH(0, 0, 1);
  asm volatile("s_waitcnt vmcnt(0)" ::: "memory");
  barrier_seq();

  int cur = 0;
  for (int t = 0; t < nt - 1; ++t) {
    const int kn = (t + 1) << 6;
    const int nx = cur ^ 1;
    // PH0: ks=0 Chalf=0
    RD_A(cur, 0, 0); RD_B(cur, 0);
    STAGE_KH(nx, kn, 0);
    barrier_seq();
    MFMA16(0);
    barrier_seq();
    // PH1: ks=0 Chalf=1 (B regs reused)
    RD_A(cur, 0, 1);
    STAGE_KH(nx, kn, 1);
    barrier_seq();
    MFMA16(1);
    asm volatile("s_waitcnt vmcnt(8)" ::: "memory");  // kh1(t) landed
    barrier_seq();
    // PH2: ks=1 Chalf=0
    RD_A(cur, 1, 0); RD_B(cur, 1);
    barrier_seq();
    MFMA16(0);
    barrier_seq();
    // PH3: ks=1 Chalf=1
    RD_A(cur, 1, 1);
    barrier_seq();
    MFMA16(1);
    asm volatile("s_waitcnt vmcnt(4)" ::: "memory");  // kh0(t+1) landed
    barrier_seq();
    cur = nx;
  }
  // epilogue tile (no prefetch): kh0 resident on entry, kh1 after vmcnt(0)
  RD_A(cur, 0, 0); RD_B(cur, 0);
  MFMA16(0);
  RD_A(cur, 0, 1);
  MFMA16(1);
  asm volatile("s_waitcnt vmcnt(0)" ::: "memory");
  barrier_seq();
  RD_A(cur, 1, 0); RD_B(cur, 1);
  MFMA16(0);
  RD_A(cur, 1, 1);
  MFMA16(1);
#undef STAGE_KH
#undef RD_A
#undef RD_B
#undef MFMA16

#pragma unroll
  for (int mi = 0; mi < 8; mi++) {
#pragma unroll
    for (int ni = 0; ni < 4; ni++) {
      int n = n0 + wn * 64 + ni * 16 + l15;       // C/D: col = lane&15
      float bvv = bias[n];
#pragma unroll
      for (int r = 0; r < 4; r++) {
        int m = m0 + wm * 128 + mi * 16 + lk * 4 + r;  // row = (lane>>4)*4 + reg
        size_t idx = (size_t)m * N + n;
        float v = acc[mi][ni][r] + bvv;
        if (EPI == 0) {
          ((u16*)outp)[idx] = f2bf(v);
        } else if (EPI == 1) {
          ((float*)outp)[idx] = v + res[idx];
        } else {
          ((u16*)outp)[idx] = f2bf(gelu_f(v));
        }
      }
    }
  }
}

// ---------------- causal decay mixing as a chunked linear scan.
__global__ __launch_bounds__(64) void scan_carry(
    const u16* __restrict__ p, const float* __restrict__ mix_w,
    const float* __restrict__ decay, float* __restrict__ carry) {
  int blk = blockIdx.x;
  int c = blk & 31, h = (blk >> 5) & 15, b = blk >> 9;
  int f = threadIdx.x;
  float d = fminf(fmaxf(decay[h], 0.9f), 1.0f);
  float r = powf(d, 0.25f);
  size_t base = ((size_t)b * TT + c * SC_L) * EE + h * HHD + f;
  const float* mw = mix_w + h * TT + c * SC_L;
  bool isRow = (h >= 8);
  float S = 0.f;
#pragma unroll 4
  for (int t = 0; t < SC_L; t++) {
    float pv = bf2f(p[base + (size_t)t * EE]);
    float q = isRow ? mw[t] * pv : pv;
    S = r * S + q;
  }
  carry[blk * 64 + f] = S;
}

__global__ __launch_bounds__(64) void scan_apply(
    const u16* __restrict__ p, const float* __restrict__ mix_w,
    const float* __restrict__ mix_b, const float* __restrict__ decay,
    const float* __restrict__ carry, u16* __restrict__ mixed) {
  int blk = blockIdx.x;
  int c = blk & 31, h = (blk >> 5) & 15, b = blk >> 9;
  int f = threadIdx.x;
  float d = fminf(fmaxf(decay[h], 0.9f), 1.0f);
  float r = powf(d, 0.25f);
  float rl = powf(r, (float)SC_L);
  int cb = blk - c;
  float S = 0.f;
  for (int cc = 0; cc < c; cc++) S = rl * S + carry[(cb + cc) * 64 + f];
  size_t base = ((size_t)b * TT + c * SC_L) * EE + h * HHD + f;
  const float* mw = mix_w + h * TT + c * SC_L;
  const float* mb = mix_b + h * TT + c * SC_L;
  bool isRow = (h >= 8);
  for (int t = 0; t < SC_L; t++) {
    float pv = bf2f(p[base + (size_t)t * EE]);
    float q = isRow ? mw[t] * pv : pv;
    S = r * S + q;
    float val = (isRow ? S : mw[t] * S) + mb[t];
    mixed[base + (size_t)t * EE] = f2bf(val);
  }
}

extern "C" void kernel_launch(void* const* d_in, const int* in_sizes, int n_in,
                              void* d_out, int out_size, void* d_ws, size_t ws_size,
                              hipStream_t stream) {
  const float* x = (const float*)d_in[0];
  const float* w_proj = (const float*)d_in[1];
  const float* b_proj = (const float*)d_in[2];
  const float* mix_w = (const float*)d_in[3];
  const float* mix_b = (const float*)d_in[4];
  const float* decay = (const float*)d_in[5];
  const float* out_w = (const float*)d_in[6];
  const float* out_b = (const float*)d_in[7];
  const float* ln1_g = (const float*)d_in[8];
  const float* ln1_b = (const float*)d_in[9];
  const float* ln2_g = (const float*)d_in[10];
  const float* ln2_b = (const float*)d_in[11];
  const float* ff_w1 = (const float*)d_in[12];
  const float* ff_b1 = (const float*)d_in[13];
  const float* ff_w2 = (const float*)d_in[14];
  const float* ff_b2 = (const float*)d_in[15];
  float* out = (float*)d_out;

  // ws layout (MiB): [0,2)Wp [2,4)Wo [4,12)W1 [12,20)W2 [20,52)mixed/g
  //                  [52,180)u (h at 52, p at 84) [180,181)carry
  char* ws = (char*)d_ws;
  const size_t MiB = 1ull << 20;
  u16* wWp = (u16*)(ws + 0 * MiB);
  u16* wWo = (u16*)(ws + 2 * MiB);
  u16* wW1 = (u16*)(ws + 4 * MiB);
  u16* wW2 = (u16*)(ws + 12 * MiB);
  u16* wMix = (u16*)(ws + 20 * MiB);
  u16* wH = (u16*)(ws + 52 * MiB);
  u16* wP = (u16*)(ws + 84 * MiB);
  u16* wU = (u16*)(ws + 52 * MiB);
  float* wCarry = (float*)(ws + 180 * MiB);

  dim3 tb(32, 8);
  transpose_to_bf16<<<dim3(2, 32, 16), tb, 0, stream>>>(w_proj, wWp, 1024, 64,
                                                        65536L, 65536L);
  transpose_to_bf16<<<dim3(32, 32, 1), tb, 0, stream>>>(out_w, wWo, 1024, 1024, 0L, 0L);
  transpose_to_bf16<<<dim3(128, 32, 1), tb, 0, stream>>>(ff_w1, wW1, 1024, 4096, 0L, 0L);
  transpose_to_bf16<<<dim3(32, 128, 1), tb, 0, stream>>>(ff_w2, wW2, 4096, 1024, 0L, 0L);

  ln_to_bf16<<<dim3(MROWS), dim3(256), 0, stream>>>(x, ln1_g, ln1_b, wH);

  gemm256<0><<<dim3(4, 64), dim3(512), 0, stream>>>(
      wH, wWp, b_proj, (const float*)nullptr, (void*)wP, MROWS, 1024, 1024);

  scan_carry<<<dim3(4096), dim3(64), 0, stream>>>(wP, mix_w, decay, wCarry);
  scan_apply<<<dim3(4096), dim3(64), 0, stream>>>(wP, mix_w, mix_b, decay, wCarry, wMix);

  gemm256<1><<<dim3(4, 64), dim3(512), 0, stream>>>(
      wMix, wWo, out_b, x, (void*)out, MROWS, 1024, 1024);

  ln_to_bf16<<<dim3(MROWS), dim3(256), 0, stream>>>(out, ln2_g, ln2_b, wMix);

  gemm256<2><<<dim3(16, 64), dim3(512), 0, stream>>>(
      wMix, wW1, ff_b1, (const float*)nullptr, (void*)wU, MROWS, 4096, 1024);

  gemm256<1><<<dim3(4, 64), dim3(512), 0, stream>>>(
      wU, wW2, ff_b2, out, (void*)out, MROWS, 1024, 4096);
}

// Round 4
// 551.785 us; speedup vs baseline: 1.1576x; 1.1576x over previous
//
#include <hip/hip_runtime.h>

// MixerBlock: B=8, T=2048, E=1024, H=16, HD=64, DFF=4096, DC=4
// GEMM: 256x256 tile, BK=64, 8 waves (2Mx4N), double-buffered 128 KiB LDS.
// 4 phases per K-tile = (Mhalf, kstep); each phase: {ds_reads || stage one
// chunk of tile t+1} -> barrier -> 16 MFMA (setprio) -> barrier.
// LDS layout (round-2 proven conflict-free): per matrix [256 rows][8 slots
// of 8 bf16] (128B rows), LDS slot s holds global slot s^(row&7), written
// via pre-swizzled global source (rule #21), read with sl = (ks*4+lk)^(l15&7).
// Counted vmcnt (per-thread, 2 gloads per stage-chunk):
//   stage order during tile t: Bh0',Bh1',Aq02',Aq13'  (for tile t+1)
//   needs: {Bh0',Bh1',Aq02'} by t+1.PH0 ; {Aq13'} by t+1.PH2
//   waits: vmcnt(4) end of PH1 (forces Aq13 of tile t), vmcnt(2) end of PH3
//   (forces Bh0',Bh1',Aq02'). Never drains to 0 in the main loop.

#define TT 2048
#define EE 1024
#define HHD 64
#define MROWS 16384
#define SC_L 64

typedef __bf16 bf16x8 __attribute__((ext_vector_type(8)));
typedef float f32x4 __attribute__((ext_vector_type(4)));
typedef unsigned short u16;
typedef unsigned int u32;

__device__ __forceinline__ u16 f2bf(float f) {
  u32 u = __builtin_bit_cast(u32, f);
  u += 0x7FFFu + ((u >> 16) & 1u);      // round-to-nearest-even
  return (u16)(u >> 16);
}
__device__ __forceinline__ float bf2f(u16 s) {
  u32 u = ((u32)s) << 16;
  return __builtin_bit_cast(float, u);
}
__device__ __forceinline__ float gelu_f(float x) {
  float u = 0.7978845608028654f * x * (1.0f + 0.044715f * x * x);
  float e = __expf(2.0f * u);
  float t = 1.0f - 2.0f / (e + 1.0f);   // tanh(u)
  return 0.5f * x * (1.0f + t);
}
__device__ __forceinline__ void gload_lds16(const void* g, void* l) {
  __builtin_amdgcn_global_load_lds(
      (const __attribute__((address_space(1))) u32*)g,
      (__attribute__((address_space(3))) u32*)l, 16, 0, 0);
}
__device__ __forceinline__ void wg_barrier() {
  asm volatile("" ::: "memory");
  __builtin_amdgcn_s_barrier();
  asm volatile("" ::: "memory");
}

// ---------------- weight transpose + cast: src (R x C) f32 -> dst (C x R) bf16
__global__ __launch_bounds__(256) void transpose_to_bf16(
    const float* __restrict__ src, u16* __restrict__ dst, int R, int C,
    long sbs, long dbs) {
  __shared__ float tile[32][33];
  src += (long)blockIdx.z * sbs;
  dst += (long)blockIdx.z * dbs;
  int c0 = blockIdx.x * 32, r0 = blockIdx.y * 32;
  int tx = threadIdx.x, ty = threadIdx.y;
#pragma unroll
  for (int i = 0; i < 4; i++)
    tile[ty + i * 8][tx] = src[(long)(r0 + ty + i * 8) * C + c0 + tx];
  __syncthreads();
#pragma unroll
  for (int i = 0; i < 4; i++)
    dst[(long)(c0 + ty + i * 8) * R + r0 + tx] = f2bf(tile[tx][ty + i * 8]);
}

// ---------------- LayerNorm over E=1024, one row per block
__global__ __launch_bounds__(256) void ln_to_bf16(
    const float* __restrict__ x, const float* __restrict__ gam,
    const float* __restrict__ bet, u16* __restrict__ y) {
  int row = blockIdx.x;
  int tid = threadIdx.x;
  float4 v = ((const float4*)x)[row * 256 + tid];
  float s = v.x + v.y + v.z + v.w;
  float s2 = v.x * v.x + v.y * v.y + v.z * v.z + v.w * v.w;
#pragma unroll
  for (int off = 1; off < 64; off <<= 1) {
    s += __shfl_xor(s, off);
    s2 += __shfl_xor(s2, off);
  }
  __shared__ float red[8];
  int w = tid >> 6;
  if ((tid & 63) == 0) { red[w] = s; red[4 + w] = s2; }
  __syncthreads();
  s = red[0] + red[1] + red[2] + red[3];
  s2 = red[4] + red[5] + red[6] + red[7];
  float mu = s * (1.0f / 1024.0f);
  float var = s2 * (1.0f / 1024.0f) - mu * mu;
  float rstd = rsqrtf(var + 1e-5f);
  int e0 = tid * 4;
  ushort4 o;
  o.x = f2bf((v.x - mu) * rstd * gam[e0 + 0] + bet[e0 + 0]);
  o.y = f2bf((v.y - mu) * rstd * gam[e0 + 1] + bet[e0 + 1]);
  o.z = f2bf((v.z - mu) * rstd * gam[e0 + 2] + bet[e0 + 2]);
  o.w = f2bf((v.w - mu) * rstd * gam[e0 + 3] + bet[e0 + 3]);
  ((ushort4*)y)[row * 256 + tid] = o;
}

// ---------------- bf16 GEMM, 256x256, BK=64, staggered counted-vmcnt pipeline.
// A: (M x K) bf16 row-major. Bt: (N x K) bf16 row-major.
// LDS buffer c at c*32768 (u16): A [0,16384), B [16384,32768).
// EPI 0: bf16 = acc+bias ; 1: f32 = acc+bias+res ; 2: bf16 = gelu(acc+bias)
template <int EPI>
__global__ __launch_bounds__(512, 2) void gemm256(
    const u16* __restrict__ A, const u16* __restrict__ Bt,
    const float* __restrict__ bias, const float* __restrict__ res, void* outp,
    int M, int N, int K) {
  __shared__ u16 lds[65536];  // 128 KiB
  const int tid = threadIdx.x;
  const int w = tid >> 6, lane = tid & 63;
  const int wm = w >> 2, wn = w & 3;
  const int l15 = lane & 15, lk = lane >> 4;

  // T1: bijective XCD swizzle (all launches have nwg % 8 == 0)
  const int gx = (int)gridDim.x;
  const int nwg = gx * (int)gridDim.y;
  const int bid = (int)blockIdx.y * gx + (int)blockIdx.x;
  const int cpx = nwg >> 3;
  const int swz = (bid & 7) * cpx + (bid >> 3);
  const int bx = swz % gx, by = swz / gx;
  const int m0 = by * 256, n0 = bx * 256;

  // Staging: one gload covers 64 rows (wave w -> rows w*8+[0,8), slot lane&7,
  // source slot pre-swizzled by row&7).
  const int srow = w * 8 + (lane >> 3);
  const int sslot = (lane & 7) ^ (lane >> 3);
  const u16* aS = A + (size_t)(m0 + srow) * K + sslot * 8;
  const u16* bS = Bt + (size_t)(n0 + srow) * K + sslot * 8;

  f32x4 acc[8][4];
  const f32x4 z = {0.f, 0.f, 0.f, 0.f};
#pragma unroll
  for (int mi = 0; mi < 8; mi++)
#pragma unroll
    for (int ni = 0; ni < 4; ni++) acc[mi][ni] = z;

  bf16x8 a[4], b0[4], b1[4];

#define STAGE_B(C, KT, H) { \
    u16* lb = lds + (C) * 32768 + 16384 + (H) * 8192 + w * 512; \
    gload_lds16(bS + (size_t)((H) * 128) * K + (KT), lb); \
    gload_lds16(bS + (size_t)((H) * 128 + 64) * K + (KT), lb + 4096); }

#define STAGE_A02(C, KT) { \
    u16* lb = lds + (C) * 32768 + w * 512; \
    gload_lds16(aS + (KT), lb); \
    gload_lds16(aS + (size_t)128 * K + (KT), lb + 8192); }

#define STAGE_A13(C, KT) { \
    u16* lb = lds + (C) * 32768 + 4096 + w * 512; \
    gload_lds16(aS + (size_t)64 * K + (KT), lb); \
    gload_lds16(aS + (size_t)192 * K + (KT), lb + 8192); }

#define RD_A(C, KS, MH) { \
    const bf16x8* lp = (const bf16x8*)(lds + (C) * 32768); \
    const int sl = ((KS) * 4 + lk) ^ (l15 & 7); \
    const int rb = wm * 128 + (MH) * 64 + l15; \
    a[0] = lp[rb * 8 + sl]; \
    a[1] = lp[(rb + 16) * 8 + sl]; \
    a[2] = lp[(rb + 32) * 8 + sl]; \
    a[3] = lp[(rb + 48) * 8 + sl]; }

#define RD_B(BV, C, KS) { \
    const bf16x8* lp = (const bf16x8*)(lds + (C) * 32768 + 16384); \
    const int sl = ((KS) * 4 + lk) ^ (l15 & 7); \
    const int rb = wn * 64 + l15; \
    BV[0] = lp[rb * 8 + sl]; \
    BV[1] = lp[(rb + 16) * 8 + sl]; \
    BV[2] = lp[(rb + 32) * 8 + sl]; \
    BV[3] = lp[(rb + 48) * 8 + sl]; }

#define MFMA16(MH, BV) { \
    __builtin_amdgcn_s_setprio(1); \
    _Pragma("unroll") \
    for (int mm = 0; mm < 4; mm++) \
      _Pragma("unroll") \
      for (int nn = 0; nn < 4; nn++) \
        acc[(MH) * 4 + mm][nn] = __builtin_amdgcn_mfma_f32_16x16x32_bf16( \
            a[mm], BV[nn], acc[(MH) * 4 + mm][nn], 0, 0, 0); \
    __builtin_amdgcn_s_setprio(0); }

  const int nt = K >> 6;
  // prologue: stage tile 0 fully into buf 0
  STAGE_B(0, 0, 0);
  STAGE_B(0, 0, 1);
  STAGE_A02(0, 0);
  STAGE_A13(0, 0);
  asm volatile("s_waitcnt vmcnt(0)" ::: "memory");
  wg_barrier();

  int cur = 0;
  for (int t = 0; t < nt - 1; ++t) {
    const int kn = (t + 1) << 6;
    const int nx = cur ^ 1;
    // PH0 (mh0, ks0)
    RD_B(b0, cur, 0);
    RD_A(cur, 0, 0);
    STAGE_B(nx, kn, 0);
    wg_barrier();
    MFMA16(0, b0);
    wg_barrier();
    // PH1 (mh0, ks1)
    RD_B(b1, cur, 1);
    RD_A(cur, 1, 0);
    STAGE_B(nx, kn, 1);
    wg_barrier();
    MFMA16(0, b1);
    asm volatile("s_waitcnt vmcnt(4)" ::: "memory");  // Aq13(t) landed
    wg_barrier();
    // PH2 (mh1, ks0) — b0 reused from regs
    RD_A(cur, 0, 1);
    STAGE_A02(nx, kn);
    wg_barrier();
    MFMA16(1, b0);
    wg_barrier();
    // PH3 (mh1, ks1) — b1 reused
    RD_A(cur, 1, 1);
    STAGE_A13(nx, kn);
    wg_barrier();
    MFMA16(1, b1);
    asm volatile("s_waitcnt vmcnt(2)" ::: "memory");  // Bh0,Bh1,Aq02(t+1) landed
    wg_barrier();
    cur = nx;
  }
  // epilogue tile: no prefetch. Bh*,Aq02 resident; Aq13 after vmcnt(0).
  RD_B(b0, cur, 0);
  RD_A(cur, 0, 0);
  MFMA16(0, b0);
  RD_B(b1, cur, 1);
  RD_A(cur, 1, 0);
  MFMA16(0, b1);
  asm volatile("s_waitcnt vmcnt(0)" ::: "memory");
  wg_barrier();
  RD_A(cur, 0, 1);
  MFMA16(1, b0);
  RD_A(cur, 1, 1);
  MFMA16(1, b1);
#undef STAGE_B
#undef STAGE_A02
#undef STAGE_A13
#undef RD_A
#undef RD_B
#undef MFMA16

#pragma unroll
  for (int mi = 0; mi < 8; mi++) {
#pragma unroll
    for (int ni = 0; ni < 4; ni++) {
      int n = n0 + wn * 64 + ni * 16 + l15;       // C/D: col = lane&15
      float bvv = bias[n];
#pragma unroll
      for (int r = 0; r < 4; r++) {
        int m = m0 + wm * 128 + mi * 16 + lk * 4 + r;  // row = (lane>>4)*4 + reg
        size_t idx = (size_t)m * N + n;
        float v = acc[mi][ni][r] + bvv;
        if (EPI == 0) {
          ((u16*)outp)[idx] = f2bf(v);
        } else if (EPI == 1) {
          ((float*)outp)[idx] = v + res[idx];
        } else {
          ((u16*)outp)[idx] = f2bf(gelu_f(v));
        }
      }
    }
  }
}

// ---------------- causal decay mixing as a chunked linear scan.
__global__ __launch_bounds__(64) void scan_carry(
    const u16* __restrict__ p, const float* __restrict__ mix_w,
    const float* __restrict__ decay, float* __restrict__ carry) {
  int blk = blockIdx.x;
  int c = blk & 31, h = (blk >> 5) & 15, b = blk >> 9;
  int f = threadIdx.x;
  float d = fminf(fmaxf(decay[h], 0.9f), 1.0f);
  float r = powf(d, 0.25f);
  size_t base = ((size_t)b * TT + c * SC_L) * EE + h * HHD + f;
  const float* mw = mix_w + h * TT + c * SC_L;
  bool isRow = (h >= 8);
  float S = 0.f;
#pragma unroll 4
  for (int t = 0; t < SC_L; t++) {
    float pv = bf2f(p[base + (size_t)t * EE]);
    float q = isRow ? mw[t] * pv : pv;
    S = r * S + q;
  }
  carry[blk * 64 + f] = S;
}

__global__ __launch_bounds__(64) void scan_apply(
    const u16* __restrict__ p, const float* __restrict__ mix_w,
    const float* __restrict__ mix_b, const float* __restrict__ decay,
    const float* __restrict__ carry, u16* __restrict__ mixed) {
  int blk = blockIdx.x;
  int c = blk & 31, h = (blk >> 5) & 15, b = blk >> 9;
  int f = threadIdx.x;
  float d = fminf(fmaxf(decay[h], 0.9f), 1.0f);
  float r = powf(d, 0.25f);
  float rl = powf(r, (float)SC_L);
  int cb = blk - c;
  float S = 0.f;
  for (int cc = 0; cc < c; cc++) S = rl * S + carry[(cb + cc) * 64 + f];
  size_t base = ((size_t)b * TT + c * SC_L) * EE + h * HHD + f;
  const float* mw = mix_w + h * TT + c * SC_L;
  const float* mb = mix_b + h * TT + c * SC_L;
  bool isRow = (h >= 8);
  for (int t = 0; t < SC_L; t++) {
    float pv = bf2f(p[base + (size_t)t * EE]);
    float q = isRow ? mw[t] * pv : pv;
    S = r * S + q;
    float val = (isRow ? S : mw[t] * S) + mb[t];
    mixed[base + (size_t)t * EE] = f2bf(val);
  }
}

extern "C" void kernel_launch(void* const* d_in, const int* in_sizes, int n_in,
                              void* d_out, int out_size, void* d_ws, size_t ws_size,
                              hipStream_t stream) {
  const float* x = (const float*)d_in[0];
  const float* w_proj = (const float*)d_in[1];
  const float* b_proj = (const float*)d_in[2];
  const float* mix_w = (const float*)d_in[3];
  const float* mix_b = (const float*)d_in[4];
  const float* decay = (const float*)d_in[5];
  const float* out_w = (const float*)d_in[6];
  const float* out_b = (const float*)d_in[7];
  const float* ln1_g = (const float*)d_in[8];
  const float* ln1_b = (const float*)d_in[9];
  const float* ln2_g = (const float*)d_in[10];
  const float* ln2_b = (const float*)d_in[11];
  const float* ff_w1 = (const float*)d_in[12];
  const float* ff_b1 = (const float*)d_in[13];
  const float* ff_w2 = (const float*)d_in[14];
  const float* ff_b2 = (const float*)d_in[15];
  float* out = (float*)d_out;

  // ws layout (MiB): [0,2)Wp [2,4)Wo [4,12)W1 [12,20)W2 [20,52)mixed/g
  //                  [52,180)u (h at 52, p at 84) [180,181)carry
  char* ws = (char*)d_ws;
  const size_t MiB = 1ull << 20;
  u16* wWp = (u16*)(ws + 0 * MiB);
  u16* wWo = (u16*)(ws + 2 * MiB);
  u16* wW1 = (u16*)(ws + 4 * MiB);
  u16* wW2 = (u16*)(ws + 12 * MiB);
  u16* wMix = (u16*)(ws + 20 * MiB);
  u16* wH = (u16*)(ws + 52 * MiB);
  u16* wP = (u16*)(ws + 84 * MiB);
  u16* wU = (u16*)(ws + 52 * MiB);
  float* wCarry = (float*)(ws + 180 * MiB);

  dim3 tb(32, 8);
  transpose_to_bf16<<<dim3(2, 32, 16), tb, 0, stream>>>(w_proj, wWp, 1024, 64,
                                                        65536L, 65536L);
  transpose_to_bf16<<<dim3(32, 32, 1), tb, 0, stream>>>(out_w, wWo, 1024, 1024, 0L, 0L);
  transpose_to_bf16<<<dim3(128, 32, 1), tb, 0, stream>>>(ff_w1, wW1, 1024, 4096, 0L, 0L);
  transpose_to_bf16<<<dim3(32, 128, 1), tb, 0, stream>>>(ff_w2, wW2, 4096, 1024, 0L, 0L);

  ln_to_bf16<<<dim3(MROWS), dim3(256), 0, stream>>>(x, ln1_g, ln1_b, wH);

  gemm256<0><<<dim3(4, 64), dim3(512), 0, stream>>>(
      wH, wWp, b_proj, (const float*)nullptr, (void*)wP, MROWS, 1024, 1024);

  scan_carry<<<dim3(4096), dim3(64), 0, stream>>>(wP, mix_w, decay, wCarry);
  scan_apply<<<dim3(4096), dim3(64), 0, stream>>>(wP, mix_w, mix_b, decay, wCarry, wMix);

  gemm256<1><<<dim3(4, 64), dim3(512), 0, stream>>>(
      wMix, wWo, out_b, x, (void*)out, MROWS, 1024, 1024);

  ln_to_bf16<<<dim3(MROWS), dim3(256), 0, stream>>>(out, ln2_g, ln2_b, wMix);

  gemm256<2><<<dim3(16, 64), dim3(512), 0, stream>>>(
      wMix, wW1, ff_b1, (const float*)nullptr, (void*)wU, MROWS, 4096, 1024);

  gemm256<1><<<dim3(4, 64), dim3(512), 0, stream>>>(
      wU, wW2, ff_b2, out, (void*)out, MROWS, 1024, 4096);
}

// Round 5
// 534.247 us; speedup vs baseline: 1.1956x; 1.0328x over previous
//
#include <hip/hip_runtime.h>

// MixerBlock: B=8, T=2048, E=1024, H=16, HD=64, DFF=4096, DC=4
// GEMM: 256x256 tile, BK=64, 8 waves (2Mx4N), double-buffered 128 KiB LDS.
// 4 phases per K-tile = (Mhalf, kstep). DEEP stagger: ALL of tile t+1's
// stage-chunks issue during tile t's PH0/PH1, giving every chunk >=4 phases
// (~2000+ cyc) of flight before its forcing vmcnt — covers HBM latency.
// Per-thread gloads: PH0 issues Bh0',Bh1',Aq02' (6), PH1 issues Aq13' (2).
// FIFO ledger: vmcnt(8) end-PH1 forces Aq13(t); vmcnt(2) end-PH3 forces
// Bh0',Bh1',Aq02'(t+1). Never drains to 0 in the main loop.
// LDS layout (proven conflict-free, r2/r4): per matrix [256 rows][8 slots of
// 8 bf16] (128B rows), LDS slot s holds global slot s^(row&7) via
// pre-swizzled global source (rule #21); read sl = (ks*4+lk)^(l15&7).

#define TT 2048
#define EE 1024
#define HHD 64
#define MROWS 16384
#define SC_L 64

typedef __bf16 bf16x8 __attribute__((ext_vector_type(8)));
typedef float f32x4 __attribute__((ext_vector_type(4)));
typedef unsigned short u16;
typedef unsigned int u32;

__device__ __forceinline__ u16 f2bf(float f) {
  u32 u = __builtin_bit_cast(u32, f);
  u += 0x7FFFu + ((u >> 16) & 1u);      // round-to-nearest-even
  return (u16)(u >> 16);
}
__device__ __forceinline__ float bf2f(u16 s) {
  u32 u = ((u32)s) << 16;
  return __builtin_bit_cast(float, u);
}
__device__ __forceinline__ float gelu_f(float x) {
  // gelu_tanh(x) = x * sigmoid(2u), u = 0.79788456*x*(1+0.044715 x^2)
  float x2 = x * x;
  float e = -1.5957691216057308f * x * __builtin_fmaf(0.044715f, x2, 1.0f);
  return x * __builtin_amdgcn_rcpf(1.0f + __expf(e));
}
__device__ __forceinline__ void gload_lds16(const void* g, void* l) {
  __builtin_amdgcn_global_load_lds(
      (const __attribute__((address_space(1))) u32*)g,
      (__attribute__((address_space(3))) u32*)l, 16, 0, 0);
}
__device__ __forceinline__ void wg_barrier() {
  asm volatile("" ::: "memory");
  __builtin_amdgcn_s_barrier();
  asm volatile("" ::: "memory");
}

// ---------------- weight transpose + cast: src (R x C) f32 -> dst (C x R) bf16
__global__ __launch_bounds__(256) void transpose_to_bf16(
    const float* __restrict__ src, u16* __restrict__ dst, int R, int C,
    long sbs, long dbs) {
  __shared__ float tile[32][33];
  src += (long)blockIdx.z * sbs;
  dst += (long)blockIdx.z * dbs;
  int c0 = blockIdx.x * 32, r0 = blockIdx.y * 32;
  int tx = threadIdx.x, ty = threadIdx.y;
#pragma unroll
  for (int i = 0; i < 4; i++)
    tile[ty + i * 8][tx] = src[(long)(r0 + ty + i * 8) * C + c0 + tx];
  __syncthreads();
#pragma unroll
  for (int i = 0; i < 4; i++)
    dst[(long)(c0 + ty + i * 8) * R + r0 + tx] = f2bf(tile[tx][ty + i * 8]);
}

// ---------------- LayerNorm over E=1024, one row per block
__global__ __launch_bounds__(256) void ln_to_bf16(
    const float* __restrict__ x, const float* __restrict__ gam,
    const float* __restrict__ bet, u16* __restrict__ y) {
  int row = blockIdx.x;
  int tid = threadIdx.x;
  float4 v = ((const float4*)x)[row * 256 + tid];
  float s = v.x + v.y + v.z + v.w;
  float s2 = v.x * v.x + v.y * v.y + v.z * v.z + v.w * v.w;
#pragma unroll
  for (int off = 1; off < 64; off <<= 1) {
    s += __shfl_xor(s, off);
    s2 += __shfl_xor(s2, off);
  }
  __shared__ float red[8];
  int w = tid >> 6;
  if ((tid & 63) == 0) { red[w] = s; red[4 + w] = s2; }
  __syncthreads();
  s = red[0] + red[1] + red[2] + red[3];
  s2 = red[4] + red[5] + red[6] + red[7];
  float mu = s * (1.0f / 1024.0f);
  float var = s2 * (1.0f / 1024.0f) - mu * mu;
  float rstd = rsqrtf(var + 1e-5f);
  int e0 = tid * 4;
  ushort4 o;
  o.x = f2bf((v.x - mu) * rstd * gam[e0 + 0] + bet[e0 + 0]);
  o.y = f2bf((v.y - mu) * rstd * gam[e0 + 1] + bet[e0 + 1]);
  o.z = f2bf((v.z - mu) * rstd * gam[e0 + 2] + bet[e0 + 2]);
  o.w = f2bf((v.w - mu) * rstd * gam[e0 + 3] + bet[e0 + 3]);
  ((ushort4*)y)[row * 256 + tid] = o;
}

// ---------------- bf16 GEMM, 256x256, BK=64, deep-staggered counted-vmcnt.
// A: (M x K) bf16 row-major. Bt: (N x K) bf16 row-major.
// LDS buffer c at c*32768 (u16): A [0,16384), B [16384,32768).
// EPI 0: bf16 = acc+bias ; 1: f32 = acc+bias+res ; 2: bf16 = gelu(acc+bias)
template <int EPI>
__global__ __launch_bounds__(512, 2) void gemm256(
    const u16* __restrict__ A, const u16* __restrict__ Bt,
    const float* __restrict__ bias, const float* __restrict__ res, void* outp,
    int M, int N, int K) {
  __shared__ u16 lds[65536];  // 128 KiB
  const int tid = threadIdx.x;
  const int w = tid >> 6, lane = tid & 63;
  const int wm = w >> 2, wn = w & 3;
  const int l15 = lane & 15, lk = lane >> 4;

  // T1: bijective XCD swizzle (all launches have nwg % 8 == 0)
  const int gx = (int)gridDim.x;
  const int nwg = gx * (int)gridDim.y;
  const int bid = (int)blockIdx.y * gx + (int)blockIdx.x;
  const int cpx = nwg >> 3;
  const int swz = (bid & 7) * cpx + (bid >> 3);
  const int bx = swz % gx, by = swz / gx;
  const int m0 = by * 256, n0 = bx * 256;

  // Staging: one gload covers 64 rows (wave w -> rows w*8+[0,8), slot lane&7,
  // source slot pre-swizzled by row&7).
  const int srow = w * 8 + (lane >> 3);
  const int sslot = (lane & 7) ^ (lane >> 3);
  const u16* aS = A + (size_t)(m0 + srow) * K + sslot * 8;
  const u16* bS = Bt + (size_t)(n0 + srow) * K + sslot * 8;

  f32x4 acc[8][4];
  const f32x4 z = {0.f, 0.f, 0.f, 0.f};
#pragma unroll
  for (int mi = 0; mi < 8; mi++)
#pragma unroll
    for (int ni = 0; ni < 4; ni++) acc[mi][ni] = z;

  bf16x8 a[4], b0[4], b1[4];

#define STAGE_B(C, KT, H) { \
    u16* lb = lds + (C) * 32768 + 16384 + (H) * 8192 + w * 512; \
    gload_lds16(bS + (size_t)((H) * 128) * K + (KT), lb); \
    gload_lds16(bS + (size_t)((H) * 128 + 64) * K + (KT), lb + 4096); }

#define STAGE_A02(C, KT) { \
    u16* lb = lds + (C) * 32768 + w * 512; \
    gload_lds16(aS + (KT), lb); \
    gload_lds16(aS + (size_t)128 * K + (KT), lb + 8192); }

#define STAGE_A13(C, KT) { \
    u16* lb = lds + (C) * 32768 + 4096 + w * 512; \
    gload_lds16(aS + (size_t)64 * K + (KT), lb); \
    gload_lds16(aS + (size_t)192 * K + (KT), lb + 8192); }

#define RD_A(C, KS, MH) { \
    const bf16x8* lp = (const bf16x8*)(lds + (C) * 32768); \
    const int sl = ((KS) * 4 + lk) ^ (l15 & 7); \
    const int rb = wm * 128 + (MH) * 64 + l15; \
    a[0] = lp[rb * 8 + sl]; \
    a[1] = lp[(rb + 16) * 8 + sl]; \
    a[2] = lp[(rb + 32) * 8 + sl]; \
    a[3] = lp[(rb + 48) * 8 + sl]; }

#define RD_B(BV, C, KS) { \
    const bf16x8* lp = (const bf16x8*)(lds + (C) * 32768 + 16384); \
    const int sl = ((KS) * 4 + lk) ^ (l15 & 7); \
    const int rb = wn * 64 + l15; \
    BV[0] = lp[rb * 8 + sl]; \
    BV[1] = lp[(rb + 16) * 8 + sl]; \
    BV[2] = lp[(rb + 32) * 8 + sl]; \
    BV[3] = lp[(rb + 48) * 8 + sl]; }

#define MFMA16(MH, BV) { \
    __builtin_amdgcn_s_setprio(1); \
    _Pragma("unroll") \
    for (int mm = 0; mm < 4; mm++) \
      _Pragma("unroll") \
      for (int nn = 0; nn < 4; nn++) \
        acc[(MH) * 4 + mm][nn] = __builtin_amdgcn_mfma_f32_16x16x32_bf16( \
            a[mm], BV[nn], acc[(MH) * 4 + mm][nn], 0, 0, 0); \
    __builtin_amdgcn_s_setprio(0); }

  const int nt = K >> 6;
  // prologue: stage tile 0 fully into buf 0
  STAGE_B(0, 0, 0);
  STAGE_B(0, 0, 1);
  STAGE_A02(0, 0);
  STAGE_A13(0, 0);
  asm volatile("s_waitcnt vmcnt(0)" ::: "memory");
  wg_barrier();

  int cur = 0;
  for (int t = 0; t < nt - 1; ++t) {
    const int kn = (t + 1) << 6;
    const int nx = cur ^ 1;
    // PH0 (mh0, ks0) — issue 6 of tile t+1's 8 stage loads NOW (deep lead)
    RD_B(b0, cur, 0);
    RD_A(cur, 0, 0);
    STAGE_B(nx, kn, 0);
    STAGE_B(nx, kn, 1);
    STAGE_A02(nx, kn);
    wg_barrier();
    MFMA16(0, b0);
    wg_barrier();
    // PH1 (mh0, ks1) — issue the last 2 (Aq13')
    RD_B(b1, cur, 1);
    RD_A(cur, 1, 0);
    STAGE_A13(nx, kn);
    wg_barrier();
    MFMA16(0, b1);
    asm volatile("s_waitcnt vmcnt(8)" ::: "memory");  // forces Aq13(t)
    wg_barrier();
    // PH2 (mh1, ks0) — b0 reused from regs
    RD_A(cur, 0, 1);
    wg_barrier();
    MFMA16(1, b0);
    wg_barrier();
    // PH3 (mh1, ks1) — b1 reused
    RD_A(cur, 1, 1);
    wg_barrier();
    MFMA16(1, b1);
    asm volatile("s_waitcnt vmcnt(2)" ::: "memory");  // forces B+Aq02(t+1)
    wg_barrier();
    cur = nx;
  }
  // epilogue tile: no prefetch. B+Aq02 resident; Aq13 after vmcnt(0).
  RD_B(b0, cur, 0);
  RD_A(cur, 0, 0);
  MFMA16(0, b0);
  RD_B(b1, cur, 1);
  RD_A(cur, 1, 0);
  MFMA16(0, b1);
  asm volatile("s_waitcnt vmcnt(0)" ::: "memory");
  wg_barrier();
  RD_A(cur, 0, 1);
  MFMA16(1, b0);
  RD_A(cur, 1, 1);
  MFMA16(1, b1);
#undef STAGE_B
#undef STAGE_A02
#undef STAGE_A13
#undef RD_A
#undef RD_B
#undef MFMA16

#pragma unroll
  for (int mi = 0; mi < 8; mi++) {
#pragma unroll
    for (int ni = 0; ni < 4; ni++) {
      int n = n0 + wn * 64 + ni * 16 + l15;       // C/D: col = lane&15
      float bvv = bias[n];
#pragma unroll
      for (int r = 0; r < 4; r++) {
        int m = m0 + wm * 128 + mi * 16 + lk * 4 + r;  // row = (lane>>4)*4 + reg
        size_t idx = (size_t)m * N + n;
        float v = acc[mi][ni][r] + bvv;
        if (EPI == 0) {
          ((u16*)outp)[idx] = f2bf(v);
        } else if (EPI == 1) {
          ((float*)outp)[idx] = v + res[idx];
        } else {
          ((u16*)outp)[idx] = f2bf(gelu_f(v));
        }
      }
    }
  }
}

// ---------------- causal decay mixing as a chunked linear scan.
__global__ __launch_bounds__(64) void scan_carry(
    const u16* __restrict__ p, const float* __restrict__ mix_w,
    const float* __restrict__ decay, float* __restrict__ carry) {
  int blk = blockIdx.x;
  int c = blk & 31, h = (blk >> 5) & 15, b = blk >> 9;
  int f = threadIdx.x;
  float d = fminf(fmaxf(decay[h], 0.9f), 1.0f);
  float r = powf(d, 0.25f);
  size_t base = ((size_t)b * TT + c * SC_L) * EE + h * HHD + f;
  const float* mw = mix_w + h * TT + c * SC_L;
  bool isRow = (h >= 8);
  float S = 0.f;
#pragma unroll 4
  for (int t = 0; t < SC_L; t++) {
    float pv = bf2f(p[base + (size_t)t * EE]);
    float q = isRow ? mw[t] * pv : pv;
    S = r * S + q;
  }
  carry[blk * 64 + f] = S;
}

__global__ __launch_bounds__(64) void scan_apply(
    const u16* __restrict__ p, const float* __restrict__ mix_w,
    const float* __restrict__ mix_b, const float* __restrict__ decay,
    const float* __restrict__ carry, u16* __restrict__ mixed) {
  int blk = blockIdx.x;
  int c = blk & 31, h = (blk >> 5) & 15, b = blk >> 9;
  int f = threadIdx.x;
  float d = fminf(fmaxf(decay[h], 0.9f), 1.0f);
  float r = powf(d, 0.25f);
  float rl = powf(r, (float)SC_L);
  int cb = blk - c;
  float S = 0.f;
  for (int cc = 0; cc < c; cc++) S = rl * S + carry[(cb + cc) * 64 + f];
  size_t base = ((size_t)b * TT + c * SC_L) * EE + h * HHD + f;
  const float* mw = mix_w + h * TT + c * SC_L;
  const float* mb = mix_b + h * TT + c * SC_L;
  bool isRow = (h >= 8);
  for (int t = 0; t < SC_L; t++) {
    float pv = bf2f(p[base + (size_t)t * EE]);
    float q = isRow ? mw[t] * pv : pv;
    S = r * S + q;
    float val = (isRow ? S : mw[t] * S) + mb[t];
    mixed[base + (size_t)t * EE] = f2bf(val);
  }
}

extern "C" void kernel_launch(void* const* d_in, const int* in_sizes, int n_in,
                              void* d_out, int out_size, void* d_ws, size_t ws_size,
                              hipStream_t stream) {
  const float* x = (const float*)d_in[0];
  const float* w_proj = (const float*)d_in[1];
  const float* b_proj = (const float*)d_in[2];
  const float* mix_w = (const float*)d_in[3];
  const float* mix_b = (const float*)d_in[4];
  const float* decay = (const float*)d_in[5];
  const float* out_w = (const float*)d_in[6];
  const float* out_b = (const float*)d_in[7];
  const float* ln1_g = (const float*)d_in[8];
  const float* ln1_b = (const float*)d_in[9];
  const float* ln2_g = (const float*)d_in[10];
  const float* ln2_b = (const float*)d_in[11];
  const float* ff_w1 = (const float*)d_in[12];
  const float* ff_b1 = (const float*)d_in[13];
  const float* ff_w2 = (const float*)d_in[14];
  const float* ff_b2 = (const float*)d_in[15];
  float* out = (float*)d_out;

  // ws layout (MiB): [0,2)Wp [2,4)Wo [4,12)W1 [12,20)W2 [20,52)mixed/g
  //                  [52,180)u (h at 52, p at 84) [180,181)carry
  char* ws = (char*)d_ws;
  const size_t MiB = 1ull << 20;
  u16* wWp = (u16*)(ws + 0 * MiB);
  u16* wWo = (u16*)(ws + 2 * MiB);
  u16* wW1 = (u16*)(ws + 4 * MiB);
  u16* wW2 = (u16*)(ws + 12 * MiB);
  u16* wMix = (u16*)(ws + 20 * MiB);
  u16* wH = (u16*)(ws + 52 * MiB);
  u16* wP = (u16*)(ws + 84 * MiB);
  u16* wU = (u16*)(ws + 52 * MiB);
  float* wCarry = (float*)(ws + 180 * MiB);

  dim3 tb(32, 8);
  transpose_to_bf16<<<dim3(2, 32, 16), tb, 0, stream>>>(w_proj, wWp, 1024, 64,
                                                        65536L, 65536L);
  transpose_to_bf16<<<dim3(32, 32, 1), tb, 0, stream>>>(out_w, wWo, 1024, 1024, 0L, 0L);
  transpose_to_bf16<<<dim3(128, 32, 1), tb, 0, stream>>>(ff_w1, wW1, 1024, 4096, 0L, 0L);
  transpose_to_bf16<<<dim3(32, 128, 1), tb, 0, stream>>>(ff_w2, wW2, 4096, 1024, 0L, 0L);

  ln_to_bf16<<<dim3(MROWS), dim3(256), 0, stream>>>(x, ln1_g, ln1_b, wH);

  gemm256<0><<<dim3(4, 64), dim3(512), 0, stream>>>(
      wH, wWp, b_proj, (const float*)nullptr, (void*)wP, MROWS, 1024, 1024);

  scan_carry<<<dim3(4096), dim3(64), 0, stream>>>(wP, mix_w, decay, wCarry);
  scan_apply<<<dim3(4096), dim3(64), 0, stream>>>(wP, mix_w, mix_b, decay, wCarry, wMix);

  gemm256<1><<<dim3(4, 64), dim3(512), 0, stream>>>(
      wMix, wWo, out_b, x, (void*)out, MROWS, 1024, 1024);

  ln_to_bf16<<<dim3(MROWS), dim3(256), 0, stream>>>(out, ln2_g, ln2_b, wMix);

  gemm256<2><<<dim3(16, 64), dim3(512), 0, stream>>>(
      wMix, wW1, ff_b1, (const float*)nullptr, (void*)wU, MROWS, 4096, 1024);

  gemm256<1><<<dim3(4, 64), dim3(512), 0, stream>>>(
      wU, wW2, ff_b2, out, (void*)out, MROWS, 1024, 4096);
}

// Round 6
// 530.762 us; speedup vs baseline: 1.2035x; 1.0066x over previous
//
#include <hip/hip_runtime.h>

// MixerBlock: B=8, T=2048, E=1024, H=16, HD=64, DFF=4096, DC=4
// GEMM: 256x256 tile, BK=64, 8 waves (2Mx4N), dbuf 128 KiB LDS, 4-phase
// counted-vmcnt K-loop (r4/r5 structure, conflict-free swizzled LDS).
// NEW (r6): L2-locality supertile swizzle — each XCD owns a (PX block-cols
// x BY block-rows) supertile, bx-fastest within it, so the B-panel set per
// XCD fits its 4 MiB L2 (kills the L3 re-stream that capped r2-r5 at
// ~770 TF) and co-resident blocks share A-panels.

#define TT 2048
#define EE 1024
#define HHD 64
#define MROWS 16384
#define SC_L 64

typedef __bf16 bf16x8 __attribute__((ext_vector_type(8)));
typedef float f32x4 __attribute__((ext_vector_type(4)));
typedef unsigned short u16;
typedef unsigned int u32;

__device__ __forceinline__ u16 f2bf(float f) {
  u32 u = __builtin_bit_cast(u32, f);
  u += 0x7FFFu + ((u >> 16) & 1u);      // round-to-nearest-even
  return (u16)(u >> 16);
}
__device__ __forceinline__ float bf2f(u16 s) {
  u32 u = ((u32)s) << 16;
  return __builtin_bit_cast(float, u);
}
__device__ __forceinline__ float gelu_f(float x) {
  // gelu_tanh(x) = x * sigmoid(2u), u = 0.79788456*x*(1+0.044715 x^2)
  float x2 = x * x;
  float e = -1.5957691216057308f * x * __builtin_fmaf(0.044715f, x2, 1.0f);
  return x * __builtin_amdgcn_rcpf(1.0f + __expf(e));
}
__device__ __forceinline__ void gload_lds16(const void* g, void* l) {
  __builtin_amdgcn_global_load_lds(
      (const __attribute__((address_space(1))) u32*)g,
      (__attribute__((address_space(3))) u32*)l, 16, 0, 0);
}
__device__ __forceinline__ void wg_barrier() {
  asm volatile("" ::: "memory");
  __builtin_amdgcn_s_barrier();
  asm volatile("" ::: "memory");
}

// ---------------- weight transpose + cast: src (R x C) f32 -> dst (C x R) bf16
__global__ __launch_bounds__(256) void transpose_to_bf16(
    const float* __restrict__ src, u16* __restrict__ dst, int R, int C,
    long sbs, long dbs) {
  __shared__ float tile[32][33];
  src += (long)blockIdx.z * sbs;
  dst += (long)blockIdx.z * dbs;
  int c0 = blockIdx.x * 32, r0 = blockIdx.y * 32;
  int tx = threadIdx.x, ty = threadIdx.y;
#pragma unroll
  for (int i = 0; i < 4; i++)
    tile[ty + i * 8][tx] = src[(long)(r0 + ty + i * 8) * C + c0 + tx];
  __syncthreads();
#pragma unroll
  for (int i = 0; i < 4; i++)
    dst[(long)(c0 + ty + i * 8) * R + r0 + tx] = f2bf(tile[tx][ty + i * 8]);
}

// ---------------- LayerNorm over E=1024, one row per block
__global__ __launch_bounds__(256) void ln_to_bf16(
    const float* __restrict__ x, const float* __restrict__ gam,
    const float* __restrict__ bet, u16* __restrict__ y) {
  int row = blockIdx.x;
  int tid = threadIdx.x;
  float4 v = ((const float4*)x)[row * 256 + tid];
  float s = v.x + v.y + v.z + v.w;
  float s2 = v.x * v.x + v.y * v.y + v.z * v.z + v.w * v.w;
#pragma unroll
  for (int off = 1; off < 64; off <<= 1) {
    s += __shfl_xor(s, off);
    s2 += __shfl_xor(s2, off);
  }
  __shared__ float red[8];
  int w = tid >> 6;
  if ((tid & 63) == 0) { red[w] = s; red[4 + w] = s2; }
  __syncthreads();
  s = red[0] + red[1] + red[2] + red[3];
  s2 = red[4] + red[5] + red[6] + red[7];
  float mu = s * (1.0f / 1024.0f);
  float var = s2 * (1.0f / 1024.0f) - mu * mu;
  float rstd = rsqrtf(var + 1e-5f);
  int e0 = tid * 4;
  ushort4 o;
  o.x = f2bf((v.x - mu) * rstd * gam[e0 + 0] + bet[e0 + 0]);
  o.y = f2bf((v.y - mu) * rstd * gam[e0 + 1] + bet[e0 + 1]);
  o.z = f2bf((v.z - mu) * rstd * gam[e0 + 2] + bet[e0 + 2]);
  o.w = f2bf((v.w - mu) * rstd * gam[e0 + 3] + bet[e0 + 3]);
  ((ushort4*)y)[row * 256 + tid] = o;
}

// ---------------- bf16 GEMM, 256x256, BK=64, counted-vmcnt pipeline,
// L2-locality supertile swizzle. A: (M x K) bf16 rm. Bt: (N x K) bf16 rm.
// LDS buffer c at c*32768 (u16): A [0,16384), B [16384,32768).
// Supertile params: px block-cols per XCD-group, gxp = gridDim.x/px XCD-
// groups along x, byper = block-rows per XCD. bid -> xcd = bid&7 owns
// supertile (xg*px..+px) x (yg*byper..+byper); i = bid>>3, bx-fastest.
// EPI 0: bf16 = acc+bias ; 1: f32 = acc+bias+res ; 2: bf16 = gelu(acc+bias)
template <int EPI>
__global__ __launch_bounds__(512, 2) void gemm256(
    const u16* __restrict__ A, const u16* __restrict__ Bt,
    const float* __restrict__ bias, const float* __restrict__ res, void* outp,
    int M, int N, int K, int px, int gxp, int byper) {
  __shared__ u16 lds[65536];  // 128 KiB
  const int tid = threadIdx.x;
  const int w = tid >> 6, lane = tid & 63;
  const int wm = w >> 2, wn = w & 3;
  const int l15 = lane & 15, lk = lane >> 4;

  // L2-locality supertile swizzle (bijective; nwg % 8 == 0 for all launches)
  const int gx = (int)gridDim.x;
  const int bid = (int)blockIdx.y * gx + (int)blockIdx.x;
  const int xcd = bid & 7, i = bid >> 3;
  const int xg = xcd % gxp, yg = xcd / gxp;
  const int bx = xg * px + (i % px);
  const int by = yg * byper + (i / px);
  const int m0 = by * 256, n0 = bx * 256;

  // Staging: one gload covers 64 rows (wave w -> rows w*8+[0,8), slot lane&7,
  // source slot pre-swizzled by row&7).
  const int srow = w * 8 + (lane >> 3);
  const int sslot = (lane & 7) ^ (lane >> 3);
  const u16* aS = A + (size_t)(m0 + srow) * K + sslot * 8;
  const u16* bS = Bt + (size_t)(n0 + srow) * K + sslot * 8;

  f32x4 acc[8][4];
  const f32x4 z = {0.f, 0.f, 0.f, 0.f};
#pragma unroll
  for (int mi = 0; mi < 8; mi++)
#pragma unroll
    for (int ni = 0; ni < 4; ni++) acc[mi][ni] = z;

  bf16x8 a[4], b0[4], b1[4];

#define STAGE_B(C, KT, H) { \
    u16* lb = lds + (C) * 32768 + 16384 + (H) * 8192 + w * 512; \
    gload_lds16(bS + (size_t)((H) * 128) * K + (KT), lb); \
    gload_lds16(bS + (size_t)((H) * 128 + 64) * K + (KT), lb + 4096); }

#define STAGE_A02(C, KT) { \
    u16* lb = lds + (C) * 32768 + w * 512; \
    gload_lds16(aS + (KT), lb); \
    gload_lds16(aS + (size_t)128 * K + (KT), lb + 8192); }

#define STAGE_A13(C, KT) { \
    u16* lb = lds + (C) * 32768 + 4096 + w * 512; \
    gload_lds16(aS + (size_t)64 * K + (KT), lb); \
    gload_lds16(aS + (size_t)192 * K + (KT), lb + 8192); }

#define RD_A(C, KS, MH) { \
    const bf16x8* lp = (const bf16x8*)(lds + (C) * 32768); \
    const int sl = ((KS) * 4 + lk) ^ (l15 & 7); \
    const int rb = wm * 128 + (MH) * 64 + l15; \
    a[0] = lp[rb * 8 + sl]; \
    a[1] = lp[(rb + 16) * 8 + sl]; \
    a[2] = lp[(rb + 32) * 8 + sl]; \
    a[3] = lp[(rb + 48) * 8 + sl]; }

#define RD_B(BV, C, KS) { \
    const bf16x8* lp = (const bf16x8*)(lds + (C) * 32768 + 16384); \
    const int sl = ((KS) * 4 + lk) ^ (l15 & 7); \
    const int rb = wn * 64 + l15; \
    BV[0] = lp[rb * 8 + sl]; \
    BV[1] = lp[(rb + 16) * 8 + sl]; \
    BV[2] = lp[(rb + 32) * 8 + sl]; \
    BV[3] = lp[(rb + 48) * 8 + sl]; }

#define MFMA16(MH, BV) { \
    __builtin_amdgcn_s_setprio(1); \
    _Pragma("unroll") \
    for (int mm = 0; mm < 4; mm++) \
      _Pragma("unroll") \
      for (int nn = 0; nn < 4; nn++) \
        acc[(MH) * 4 + mm][nn] = __builtin_amdgcn_mfma_f32_16x16x32_bf16( \
            a[mm], BV[nn], acc[(MH) * 4 + mm][nn], 0, 0, 0); \
    __builtin_amdgcn_s_setprio(0); }

  const int nt = K >> 6;
  // prologue: stage tile 0 fully into buf 0
  STAGE_B(0, 0, 0);
  STAGE_B(0, 0, 1);
  STAGE_A02(0, 0);
  STAGE_A13(0, 0);
  asm volatile("s_waitcnt vmcnt(0)" ::: "memory");
  wg_barrier();

  int cur = 0;
  for (int t = 0; t < nt - 1; ++t) {
    const int kn = (t + 1) << 6;
    const int nx = cur ^ 1;
    // PH0 (mh0, ks0) — issue 6 of tile t+1's 8 stage loads (deep lead)
    RD_B(b0, cur, 0);
    RD_A(cur, 0, 0);
    STAGE_B(nx, kn, 0);
    STAGE_B(nx, kn, 1);
    STAGE_A02(nx, kn);
    wg_barrier();
    MFMA16(0, b0);
    wg_barrier();
    // PH1 (mh0, ks1) — issue the last 2 (Aq13')
    RD_B(b1, cur, 1);
    RD_A(cur, 1, 0);
    STAGE_A13(nx, kn);
    wg_barrier();
    MFMA16(0, b1);
    asm volatile("s_waitcnt vmcnt(8)" ::: "memory");  // forces Aq13(t)
    wg_barrier();
    // PH2 (mh1, ks0) — b0 reused from regs
    RD_A(cur, 0, 1);
    wg_barrier();
    MFMA16(1, b0);
    wg_barrier();
    // PH3 (mh1, ks1) — b1 reused
    RD_A(cur, 1, 1);
    wg_barrier();
    MFMA16(1, b1);
    asm volatile("s_waitcnt vmcnt(2)" ::: "memory");  // forces B+Aq02(t+1)
    wg_barrier();
    cur = nx;
  }
  // epilogue tile: no prefetch. B+Aq02 resident; Aq13 after vmcnt(0).
  RD_B(b0, cur, 0);
  RD_A(cur, 0, 0);
  MFMA16(0, b0);
  RD_B(b1, cur, 1);
  RD_A(cur, 1, 0);
  MFMA16(0, b1);
  asm volatile("s_waitcnt vmcnt(0)" ::: "memory");
  wg_barrier();
  RD_A(cur, 0, 1);
  MFMA16(1, b0);
  RD_A(cur, 1, 1);
  MFMA16(1, b1);
#undef STAGE_B
#undef STAGE_A02
#undef STAGE_A13
#undef RD_A
#undef RD_B
#undef MFMA16

#pragma unroll
  for (int mi = 0; mi < 8; mi++) {
#pragma unroll
    for (int ni = 0; ni < 4; ni++) {
      int n = n0 + wn * 64 + ni * 16 + l15;       // C/D: col = lane&15
      float bvv = bias[n];
#pragma unroll
      for (int r = 0; r < 4; r++) {
        int m = m0 + wm * 128 + mi * 16 + lk * 4 + r;  // row = (lane>>4)*4 + reg
        size_t idx = (size_t)m * N + n;
        float v = acc[mi][ni][r] + bvv;
        if (EPI == 0) {
          ((u16*)outp)[idx] = f2bf(v);
        } else if (EPI == 1) {
          ((float*)outp)[idx] = v + res[idx];
        } else {
          ((u16*)outp)[idx] = f2bf(gelu_f(v));
        }
      }
    }
  }
}

// ---------------- causal decay mixing as a chunked linear scan.
__global__ __launch_bounds__(64) void scan_carry(
    const u16* __restrict__ p, const float* __restrict__ mix_w,
    const float* __restrict__ decay, float* __restrict__ carry) {
  int blk = blockIdx.x;
  int c = blk & 31, h = (blk >> 5) & 15, b = blk >> 9;
  int f = threadIdx.x;
  float d = fminf(fmaxf(decay[h], 0.9f), 1.0f);
  float r = powf(d, 0.25f);
  size_t base = ((size_t)b * TT + c * SC_L) * EE + h * HHD + f;
  const float* mw = mix_w + h * TT + c * SC_L;
  bool isRow = (h >= 8);
  float S = 0.f;
#pragma unroll 4
  for (int t = 0; t < SC_L; t++) {
    float pv = bf2f(p[base + (size_t)t * EE]);
    float q = isRow ? mw[t] * pv : pv;
    S = r * S + q;
  }
  carry[blk * 64 + f] = S;
}

__global__ __launch_bounds__(64) void scan_apply(
    const u16* __restrict__ p, const float* __restrict__ mix_w,
    const float* __restrict__ mix_b, const float* __restrict__ decay,
    const float* __restrict__ carry, u16* __restrict__ mixed) {
  int blk = blockIdx.x;
  int c = blk & 31, h = (blk >> 5) & 15, b = blk >> 9;
  int f = threadIdx.x;
  float d = fminf(fmaxf(decay[h], 0.9f), 1.0f);
  float r = powf(d, 0.25f);
  float rl = powf(r, (float)SC_L);
  int cb = blk - c;
  float S = 0.f;
  for (int cc = 0; cc < c; cc++) S = rl * S + carry[(cb + cc) * 64 + f];
  size_t base = ((size_t)b * TT + c * SC_L) * EE + h * HHD + f;
  const float* mw = mix_w + h * TT + c * SC_L;
  const float* mb = mix_b + h * TT + c * SC_L;
  bool isRow = (h >= 8);
  for (int t = 0; t < SC_L; t++) {
    float pv = bf2f(p[base + (size_t)t * EE]);
    float q = isRow ? mw[t] * pv : pv;
    S = r * S + q;
    float val = (isRow ? S : mw[t] * S) + mb[t];
    mixed[base + (size_t)t * EE] = f2bf(val);
  }
}

extern "C" void kernel_launch(void* const* d_in, const int* in_sizes, int n_in,
                              void* d_out, int out_size, void* d_ws, size_t ws_size,
                              hipStream_t stream) {
  const float* x = (const float*)d_in[0];
  const float* w_proj = (const float*)d_in[1];
  const float* b_proj = (const float*)d_in[2];
  const float* mix_w = (const float*)d_in[3];
  const float* mix_b = (const float*)d_in[4];
  const float* decay = (const float*)d_in[5];
  const float* out_w = (const float*)d_in[6];
  const float* out_b = (const float*)d_in[7];
  const float* ln1_g = (const float*)d_in[8];
  const float* ln1_b = (const float*)d_in[9];
  const float* ln2_g = (const float*)d_in[10];
  const float* ln2_b = (const float*)d_in[11];
  const float* ff_w1 = (const float*)d_in[12];
  const float* ff_b1 = (const float*)d_in[13];
  const float* ff_w2 = (const float*)d_in[14];
  const float* ff_b2 = (const float*)d_in[15];
  float* out = (float*)d_out;

  // ws layout (MiB): [0,2)Wp [2,4)Wo [4,12)W1 [12,20)W2 [20,52)mixed/g
  //                  [52,180)u (h at 52, p at 84) [180,181)carry
  char* ws = (char*)d_ws;
  const size_t MiB = 1ull << 20;
  u16* wWp = (u16*)(ws + 0 * MiB);
  u16* wWo = (u16*)(ws + 2 * MiB);
  u16* wW1 = (u16*)(ws + 4 * MiB);
  u16* wW2 = (u16*)(ws + 12 * MiB);
  u16* wMix = (u16*)(ws + 20 * MiB);
  u16* wH = (u16*)(ws + 52 * MiB);
  u16* wP = (u16*)(ws + 84 * MiB);
  u16* wU = (u16*)(ws + 52 * MiB);
  float* wCarry = (float*)(ws + 180 * MiB);

  dim3 tb(32, 8);
  transpose_to_bf16<<<dim3(2, 32, 16), tb, 0, stream>>>(w_proj, wWp, 1024, 64,
                                                        65536L, 65536L);
  transpose_to_bf16<<<dim3(32, 32, 1), tb, 0, stream>>>(out_w, wWo, 1024, 1024, 0L, 0L);
  transpose_to_bf16<<<dim3(128, 32, 1), tb, 0, stream>>>(ff_w1, wW1, 1024, 4096, 0L, 0L);
  transpose_to_bf16<<<dim3(32, 128, 1), tb, 0, stream>>>(ff_w2, wW2, 4096, 1024, 0L, 0L);

  ln_to_bf16<<<dim3(MROWS), dim3(256), 0, stream>>>(x, ln1_g, ln1_b, wH);

  // G1: gx=4 -> px=4 (B 2MB fully L2/XCD), gxp=1, byper=8
  gemm256<0><<<dim3(4, 64), dim3(512), 0, stream>>>(
      wH, wWp, b_proj, (const float*)nullptr, (void*)wP, MROWS, 1024, 1024,
      4, 1, 8);

  scan_carry<<<dim3(4096), dim3(64), 0, stream>>>(wP, mix_w, decay, wCarry);
  scan_apply<<<dim3(4096), dim3(64), 0, stream>>>(wP, mix_w, mix_b, decay, wCarry, wMix);

  // G2: same shape as G1
  gemm256<1><<<dim3(4, 64), dim3(512), 0, stream>>>(
      wMix, wWo, out_b, x, (void*)out, MROWS, 1024, 1024,
      4, 1, 8);

  ln_to_bf16<<<dim3(MROWS), dim3(256), 0, stream>>>(out, ln2_g, ln2_b, wMix);

  // G3: gx=16 -> px=4 (B-set 2MB/XCD in L2), gxp=4, byper=32
  gemm256<2><<<dim3(16, 64), dim3(512), 0, stream>>>(
      wMix, wW1, ff_b1, (const float*)nullptr, (void*)wU, MROWS, 4096, 1024,
      4, 4, 32);

  // G4: gx=4 -> px=2 (B-set 4MB/XCD in L2; A re-read 2x from HBM), gxp=2, byper=16
  gemm256<1><<<dim3(4, 64), dim3(512), 0, stream>>>(
      wU, wW2, ff_b2, out, (void*)out, MROWS, 1024, 4096,
      2, 2, 16);
}